// Round 4
// baseline (174.449 us; speedup 1.0000x reference)
//
#include <hip/hip_runtime.h>

typedef _Float16 f16;
typedef _Float16 f16x8 __attribute__((ext_vector_type(8)));
typedef float f32x4 __attribute__((ext_vector_type(4)));

#define ZC 32
#define HW 1024
#define TPB 256
#define VCH 256           // codes per LDS chunk (16 KB hi-only)
#define ZROWS_BLK 256     // z-rows per block (4 waves x 4 z-tiles x 16)
#define DELTA 0.004f      // screen margin: > 2x worst-case |S - S_hihi| (~9.8e-4)

__device__ __forceinline__ unsigned int fkey(float x) {
    unsigned int b = __float_as_uint(x);
    return (b & 0x80000000u) ? ~b : (b | 0x80000000u);
}
__device__ __forceinline__ float unfkey(unsigned int k) {
    unsigned int b = (k & 0x80000000u) ? (k & 0x7FFFFFFFu) : ~k;
    return __uint_as_float(b);
}

// Fused prep:
//  blocks [0, zblocks): normalize z rows (4-lane shfl reduce), emit f16-hi MFMA
//    B-fragments (ZFh) + f32 normalized rows (Zn); init packed/rowmax.
//  blocks [zblocks, ..): normalize codebook rows -> e (f32) + Eh (f16 hi).
__global__ void kprep(const float* __restrict__ z, const float* __restrict__ emb,
                      float* __restrict__ e, f16* __restrict__ Eh,
                      f16x8* __restrict__ ZFh, float* __restrict__ Zn,
                      unsigned long long* __restrict__ packed,
                      unsigned int* __restrict__ rowmax,
                      int N, int V, int zblocks) {
    const int blk = blockIdx.x;
    if (blk < zblocks) {
        int t = blk * TPB + threadIdx.x;
        int lane = t & 63, zt = t >> 6;
        int n = zt * 16 + (lane & 15);
        int b = n >> 10, hw = n & 1023;
        int kb = (lane >> 4) * 8;
        float x[8];
        float s = 0.f;
#pragma unroll
        for (int j = 0; j < 8; ++j) {
            x[j] = z[((size_t)(b * ZC + kb + j)) * HW + hw];
            s += x[j] * x[j];
        }
        // full row norm: 4 lane-groups {lane, lane^16, lane^32, lane^48} share row n
        s += __shfl_xor(s, 16);
        s += __shfl_xor(s, 32);
        float inv = 1.0f / fmaxf(sqrtf(s), 1e-12f);
        f16x8 h;
        float4 zn0, zn1;
#pragma unroll
        for (int j = 0; j < 8; ++j) {
            float xn = x[j] * inv;
            h[j] = (f16)xn;
            if (j < 4) ((float*)&zn0)[j] = xn; else ((float*)&zn1)[j - 4] = xn;
        }
        ZFh[t] = h;
        float4* zr = (float4*)(Zn + (size_t)n * ZC + kb);
        zr[0] = zn0; zr[1] = zn1;
        // init packed + rowmax (zblocks * 64 == N)
        int p0 = blk * 64 + threadIdx.x;
        if (threadIdx.x < 64) { packed[p0] = 0ull; rowmax[p0] = 0u; }
    } else {
        int r = (blk - zblocks) * TPB + threadIdx.x;
        if (r >= V) return;
        const float4* src = reinterpret_cast<const float4*>(emb) + (size_t)r * 8;
        float4 v[8];
        float s = 0.f;
#pragma unroll
        for (int j = 0; j < 8; ++j) {
            v[j] = src[j];
            s += v[j].x * v[j].x + v[j].y * v[j].y + v[j].z * v[j].z + v[j].w * v[j].w;
        }
        float inv = 1.0f / fmaxf(sqrtf(s), 1e-12f);
        float4* dst = reinterpret_cast<float4*>(e) + (size_t)r * 8;
        f16* eh = Eh + (size_t)r * ZC;
#pragma unroll
        for (int j = 0; j < 8; ++j) {
            float t0 = v[j].x * inv, t1 = v[j].y * inv, t2 = v[j].z * inv, t3 = v[j].w * inv;
            float4 o; o.x = t0; o.y = t1; o.z = t2; o.w = t3;
            dst[j] = o;
            eh[4 * j + 0] = (f16)t0; eh[4 * j + 1] = (f16)t1;
            eh[4 * j + 2] = (f16)t2; eh[4 * j + 3] = (f16)t3;
        }
    }
}

// K1: screen. hi*hi GEMM, per-z-row running MAX only (no index). 8 waves/SIMD.
__global__ __launch_bounds__(TPB, 8) void kscreen(const f16x8* __restrict__ ZFh,
                                                  const uint4* __restrict__ Eh,
                                                  unsigned int* __restrict__ rowmax) {
    __shared__ uint4 sEh[VCH * 4];   // 256 rows x 4 16B-chunks, XOR-swizzled
    const int tid = threadIdx.x;
    const int zb = blockIdx.x & 63;
    const int cb = blockIdx.x >> 6;

    {
        const uint4* gh = Eh + (size_t)cb * (VCH * 4);
#pragma unroll
        for (int i = 0; i < 4; ++i) {
            int c = tid + i * TPB;
            int r = c >> 2, q = c & 3;
            sEh[(r << 2) | (q ^ ((r >> 1) & 3))] = gh[c];
        }
    }

    const int lane = tid & 63;
    const int wv = tid >> 6;
    const int zt0 = (zb * 4 + wv) * 4;

    f16x8 Bh[4];
#pragma unroll
    for (int i = 0; i < 4; ++i) Bh[i] = ZFh[(size_t)(zt0 + i) * 64 + lane];
    __syncthreads();

    const int r15 = lane & 15, qq = lane >> 4;
    const int laneA = (r15 << 2) | (qq ^ ((r15 >> 1) & 3));

    float bv[4] = {-1e38f, -1e38f, -1e38f, -1e38f};
#pragma unroll
    for (int ct = 0; ct < VCH / 16; ++ct) {
        uint4 araw = sEh[ct * 64 + laneA];
        f16x8 Ah = *(const f16x8*)&araw;
#pragma unroll
        for (int i = 0; i < 4; ++i) {
            f32x4 acc = {0.f, 0.f, 0.f, 0.f};
            acc = __builtin_amdgcn_mfma_f32_16x16x32_f16(Ah, Bh[i], acc, 0, 0, 0);
            bv[i] = fmaxf(bv[i],
                          fmaxf(fmaxf(acc[0], acc[1]), fmaxf(acc[2], acc[3])));
        }
    }

#pragma unroll
    for (int i = 0; i < 4; ++i) {
        float v = bv[i];
        v = fmaxf(v, __shfl_xor(v, 16));
        v = fmaxf(v, __shfl_xor(v, 32));
        if (lane < 16) atomicMax(&rowmax[(size_t)(zt0 + i) * 16 + r15], fkey(v));
    }
}

// K2: refine. Recompute hi*hi scores (bit-identical); where a tile's max >= rowmax-DELTA,
// compute the exact f32 dot and atomicMax the packed (fkey<<32 | inv-idx) key.
__global__ __launch_bounds__(TPB, 4) void krefine(const f16x8* __restrict__ ZFh,
                                                  const uint4* __restrict__ Eh,
                                                  const float* __restrict__ e,
                                                  const float* __restrict__ Zn,
                                                  const unsigned int* __restrict__ rowmax,
                                                  unsigned long long* __restrict__ packed,
                                                  int Vm1) {
    __shared__ uint4 sEh[VCH * 4];
    const int tid = threadIdx.x;
    const int zb = blockIdx.x & 63;
    const int cb = blockIdx.x >> 6;

    {
        const uint4* gh = Eh + (size_t)cb * (VCH * 4);
#pragma unroll
        for (int i = 0; i < 4; ++i) {
            int c = tid + i * TPB;
            int r = c >> 2, q = c & 3;
            sEh[(r << 2) | (q ^ ((r >> 1) & 3))] = gh[c];
        }
    }

    const int lane = tid & 63;
    const int wv = tid >> 6;
    const int zt0 = (zb * 4 + wv) * 4;

    f16x8 Bh[4];
    float thr[4];
#pragma unroll
    for (int i = 0; i < 4; ++i) {
        Bh[i] = ZFh[(size_t)(zt0 + i) * 64 + lane];
        thr[i] = unfkey(rowmax[(size_t)(zt0 + i) * 16 + (lane & 15)]) - DELTA;
    }
    __syncthreads();

    const int r15 = lane & 15, qq = lane >> 4;
    const int laneA = (r15 << 2) | (qq ^ ((r15 >> 1) & 3));

#pragma unroll
    for (int ct = 0; ct < VCH / 16; ++ct) {
        uint4 araw = sEh[ct * 64 + laneA];
        f16x8 Ah = *(const f16x8*)&araw;
#pragma unroll
        for (int i = 0; i < 4; ++i) {
            f32x4 acc = {0.f, 0.f, 0.f, 0.f};
            acc = __builtin_amdgcn_mfma_f32_16x16x32_f16(Ah, Bh[i], acc, 0, 0, 0);
            float t4 = fmaxf(fmaxf(acc[0], acc[1]), fmaxf(acc[2], acc[3]));
            if (__any(t4 >= thr[i])) {
#pragma unroll
                for (int r = 0; r < 4; ++r) {
                    if (acc[r] >= thr[i]) {
                        int code = cb * VCH + ct * 16 + qq * 4 + r;
                        int row = (zt0 + i) * 16 + r15;
                        const float4* er = (const float4*)e + (size_t)code * 8;
                        const float4* zr = (const float4*)Zn + (size_t)row * 8;
                        float s = 0.f;
#pragma unroll
                        for (int q = 0; q < 8; ++q) {
                            float4 a = er[q], b = zr[q];
                            s = fmaf(a.x, b.x, s); s = fmaf(a.y, b.y, s);
                            s = fmaf(a.z, b.z, s); s = fmaf(a.w, b.w, s);
                        }
                        unsigned long long key =
                            ((unsigned long long)fkey(s) << 32) |
                            (unsigned int)(Vm1 - code);
                        atomicMax(&packed[row], key);
                    }
                }
            }
        }
    }
}

// Final: decode idx, gather normalized code, write z_q (b,c,h,w), partial loss per block.
__global__ void kfinal(const float* __restrict__ z, const float* __restrict__ e,
                       const unsigned long long* __restrict__ packed,
                       float* __restrict__ out, float* __restrict__ partial, int V) {
    __shared__ float red[TPB];
    int n = blockIdx.x * TPB + threadIdx.x;
    int b = n >> 10, hw = n & 1023;
    unsigned long long p = packed[n];
    int idx = (V - 1) - (int)(unsigned int)(p & 0xFFFFFFFFull);

    float zrow[ZC];
    float s = 0.f;
#pragma unroll
    for (int c = 0; c < ZC; ++c) {
        float t = z[((size_t)b * ZC + c) * HW + hw];
        zrow[c] = t;
        s += t * t;
    }
    float inv = 1.0f / fmaxf(sqrtf(s), 1e-12f);

    const float4* er = reinterpret_cast<const float4*>(e) + (size_t)idx * 8;
    float loss = 0.f;
#pragma unroll
    for (int q = 0; q < 8; ++q) {
        float4 ev = er[q];
        float d0 = ev.x - zrow[4 * q + 0] * inv;
        float d1 = ev.y - zrow[4 * q + 1] * inv;
        float d2 = ev.z - zrow[4 * q + 2] * inv;
        float d3 = ev.w - zrow[4 * q + 3] * inv;
        loss += d0 * d0 + d1 * d1 + d2 * d2 + d3 * d3;
        out[((size_t)b * ZC + (4 * q + 0)) * HW + hw] = ev.x;
        out[((size_t)b * ZC + (4 * q + 1)) * HW + hw] = ev.y;
        out[((size_t)b * ZC + (4 * q + 2)) * HW + hw] = ev.z;
        out[((size_t)b * ZC + (4 * q + 3)) * HW + hw] = ev.w;
    }

    red[threadIdx.x] = loss;
    __syncthreads();
    for (int st = TPB / 2; st > 0; st >>= 1) {
        if (threadIdx.x < st) red[threadIdx.x] += red[threadIdx.x + st];
        __syncthreads();
    }
    if (threadIdx.x == 0) partial[blockIdx.x] = red[0];
}

__global__ void kloss(const float* __restrict__ partial, float* __restrict__ out,
                      int nblocks, int NC) {
    int lane = threadIdx.x;
    float s = (lane < nblocks) ? partial[lane] : 0.f;
#pragma unroll
    for (int off = 32; off > 0; off >>= 1) s += __shfl_down(s, off);
    if (lane == 0) {
        float mean = s / (float)NC;
        out[NC] = mean;             // vq_loss
        out[NC + 1] = 0.25f * mean; // commit_loss (BETA = 0.25)
    }
}

extern "C" void kernel_launch(void* const* d_in, const int* in_sizes, int n_in,
                              void* d_out, int out_size, void* d_ws, size_t ws_size,
                              hipStream_t stream) {
    const float* z = (const float*)d_in[0];
    const float* emb = (const float*)d_in[1];
    float* out = (float*)d_out;

    const int N = in_sizes[0] / ZC;   // 16384
    const int V = in_sizes[1] / ZC;   // 8192

    // workspace layout (16B-aligned)
    char* ws = (char*)d_ws;
    float* e = (float*)ws;                                    // 1 MB
    f16* Eh = (f16*)(ws + (size_t)V * ZC * 4);                // 0.5 MB
    f16x8* ZFh = (f16x8*)(ws + (size_t)V * ZC * 6);           // 1 MB (N*4 frags)
    float* Zn = (float*)(ws + (size_t)V * ZC * 6 + (size_t)N * ZC * 2);   // 2 MB
    unsigned int* rowmax =
        (unsigned int*)(ws + (size_t)V * ZC * 6 + (size_t)N * ZC * 6);    // 64 KB
    unsigned long long* packed =
        (unsigned long long*)((char*)rowmax + (size_t)N * 4);             // 128 KB
    float* partial = (float*)((char*)packed + (size_t)N * 8);

    const int zblocks = (N * 4 + TPB - 1) / TPB;   // 256
    const int eblocks = (V + TPB - 1) / TPB;       // 32
    const int grid = (V / VCH) * (N / ZROWS_BLK);  // 32 * 64 = 2048

    kprep<<<zblocks + eblocks, TPB, 0, stream>>>(z, emb, e, Eh, ZFh, Zn,
                                                 packed, rowmax, N, V, zblocks);
    kscreen<<<grid, TPB, 0, stream>>>(ZFh, (const uint4*)Eh, rowmax);
    krefine<<<grid, TPB, 0, stream>>>(ZFh, (const uint4*)Eh, e, Zn, rowmax,
                                      packed, V - 1);
    kfinal<<<N / TPB, TPB, 0, stream>>>(z, e, packed, out, partial, V);
    kloss<<<1, 64, 0, stream>>>(partial, out, N / TPB, N * ZC);
}

// Round 5
// 90.775 us; speedup vs baseline: 1.9218x; 1.9218x over previous
//
#include <hip/hip_runtime.h>

typedef _Float16 f16;
typedef _Float16 f16x8 __attribute__((ext_vector_type(8)));
typedef float f32x4 __attribute__((ext_vector_type(4)));

#define ZC 32
#define HW 1024
#define TPB 256
#define VCH 256           // codes per LDS chunk (16 KB hi-only)
#define ZROWS_BLK 256     // z-rows per block (4 waves x 4 z-tiles x 16)
#define DELTA 0.004f      // screen margin: > 2x worst-case |S - S_hihi| (~9.8e-4)

__device__ __forceinline__ unsigned int fkey(float x) {
    unsigned int b = __float_as_uint(x);
    return (b & 0x80000000u) ? ~b : (b | 0x80000000u);
}
__device__ __forceinline__ float unfkey(unsigned int k) {
    unsigned int b = (k & 0x80000000u) ? (k & 0x7FFFFFFFu) : ~k;
    return __uint_as_float(b);
}

// Fused prep:
//  blocks [0, zblocks): normalize z rows (shfl reduce), emit f16-hi MFMA
//    B-fragments (ZFh) + f32 normalized rows (Zn); init packed/rowmax.
//  blocks [zblocks, ..): normalize codebook rows -> e (f32) + Eh (f16 hi).
__global__ void kprep(const float* __restrict__ z, const float* __restrict__ emb,
                      float* __restrict__ e, f16* __restrict__ Eh,
                      f16x8* __restrict__ ZFh, float* __restrict__ Zn,
                      unsigned long long* __restrict__ packed,
                      unsigned int* __restrict__ rowmax,
                      int N, int V, int zblocks) {
    const int blk = blockIdx.x;
    if (blk < zblocks) {
        int t = blk * TPB + threadIdx.x;
        int lane = t & 63, zt = t >> 6;
        int n = zt * 16 + (lane & 15);
        int b = n >> 10, hw = n & 1023;
        int kb = (lane >> 4) * 8;
        float x[8];
        float s = 0.f;
#pragma unroll
        for (int j = 0; j < 8; ++j) {
            x[j] = z[((size_t)(b * ZC + kb + j)) * HW + hw];
            s += x[j] * x[j];
        }
        // full row norm: lane-groups {lane^16, lane^32} share row n
        s += __shfl_xor(s, 16);
        s += __shfl_xor(s, 32);
        float inv = 1.0f / fmaxf(sqrtf(s), 1e-12f);
        f16x8 h;
        float4 zn0, zn1;
#pragma unroll
        for (int j = 0; j < 8; ++j) {
            float xn = x[j] * inv;
            h[j] = (f16)xn;
            if (j < 4) ((float*)&zn0)[j] = xn; else ((float*)&zn1)[j - 4] = xn;
        }
        ZFh[t] = h;
        float4* zr = (float4*)(Zn + (size_t)n * ZC + kb);
        zr[0] = zn0; zr[1] = zn1;
        // init packed + rowmax (zblocks * 64 == N)
        int p0 = blk * 64 + threadIdx.x;
        if (threadIdx.x < 64) { packed[p0] = 0ull; rowmax[p0] = 0u; }
    } else {
        int r = (blk - zblocks) * TPB + threadIdx.x;
        if (r >= V) return;
        const float4* src = reinterpret_cast<const float4*>(emb) + (size_t)r * 8;
        float4 v[8];
        float s = 0.f;
#pragma unroll
        for (int j = 0; j < 8; ++j) {
            v[j] = src[j];
            s += v[j].x * v[j].x + v[j].y * v[j].y + v[j].z * v[j].z + v[j].w * v[j].w;
        }
        float inv = 1.0f / fmaxf(sqrtf(s), 1e-12f);
        float4* dst = reinterpret_cast<float4*>(e) + (size_t)r * 8;
        f16* eh = Eh + (size_t)r * ZC;
#pragma unroll
        for (int j = 0; j < 8; ++j) {
            float t0 = v[j].x * inv, t1 = v[j].y * inv, t2 = v[j].z * inv, t3 = v[j].w * inv;
            float4 o; o.x = t0; o.y = t1; o.z = t2; o.w = t3;
            dst[j] = o;
            eh[4 * j + 0] = (f16)t0; eh[4 * j + 1] = (f16)t1;
            eh[4 * j + 2] = (f16)t2; eh[4 * j + 3] = (f16)t3;
        }
    }
}

// K1: screen. hi*hi GEMM, per-z-row running MAX only (no index).
// launch_bounds min-waves=4 -> 128-VGPR budget: B-fragments stay in registers
// (round 4's min-waves=8 capped at 64 VGPR and spilled Bh[] to scratch ->
//  459 MB of HBM scratch traffic, 143 us).
__global__ __launch_bounds__(TPB, 4) void kscreen(const f16x8* __restrict__ ZFh,
                                                  const uint4* __restrict__ Eh,
                                                  unsigned int* __restrict__ rowmax) {
    __shared__ uint4 sEh[VCH * 4];   // 256 rows x 4 16B-chunks, XOR-swizzled
    const int tid = threadIdx.x;
    const int zb = blockIdx.x & 63;
    const int cb = blockIdx.x >> 6;

    {
        const uint4* gh = Eh + (size_t)cb * (VCH * 4);
#pragma unroll
        for (int i = 0; i < 4; ++i) {
            int c = tid + i * TPB;
            int r = c >> 2, q = c & 3;
            sEh[(r << 2) | (q ^ ((r >> 1) & 3))] = gh[c];
        }
    }

    const int lane = tid & 63;
    const int wv = tid >> 6;
    const int zt0 = (zb * 4 + wv) * 4;

    f16x8 Bh[4];
#pragma unroll
    for (int i = 0; i < 4; ++i) Bh[i] = ZFh[(size_t)(zt0 + i) * 64 + lane];
    __syncthreads();

    const int r15 = lane & 15, qq = lane >> 4;
    const int laneA = (r15 << 2) | (qq ^ ((r15 >> 1) & 3));

    float bv[4] = {-1e38f, -1e38f, -1e38f, -1e38f};
#pragma unroll
    for (int ct = 0; ct < VCH / 16; ++ct) {
        uint4 araw = sEh[ct * 64 + laneA];
        f16x8 Ah = *(const f16x8*)&araw;
#pragma unroll
        for (int i = 0; i < 4; ++i) {
            f32x4 acc = {0.f, 0.f, 0.f, 0.f};
            acc = __builtin_amdgcn_mfma_f32_16x16x32_f16(Ah, Bh[i], acc, 0, 0, 0);
            bv[i] = fmaxf(bv[i],
                          fmaxf(fmaxf(acc[0], acc[1]), fmaxf(acc[2], acc[3])));
        }
    }

#pragma unroll
    for (int i = 0; i < 4; ++i) {
        float v = bv[i];
        v = fmaxf(v, __shfl_xor(v, 16));
        v = fmaxf(v, __shfl_xor(v, 32));
        if (lane < 16) atomicMax(&rowmax[(size_t)(zt0 + i) * 16 + r15], fkey(v));
    }
}

// K2: refine. Recompute hi*hi scores (bit-identical); where a score >= rowmax-DELTA,
// compute the exact f32 dot and atomicMax the packed (fkey<<32 | inv-idx) key.
__global__ __launch_bounds__(TPB, 4) void krefine(const f16x8* __restrict__ ZFh,
                                                  const uint4* __restrict__ Eh,
                                                  const float* __restrict__ e,
                                                  const float* __restrict__ Zn,
                                                  const unsigned int* __restrict__ rowmax,
                                                  unsigned long long* __restrict__ packed,
                                                  int Vm1) {
    __shared__ uint4 sEh[VCH * 4];
    const int tid = threadIdx.x;
    const int zb = blockIdx.x & 63;
    const int cb = blockIdx.x >> 6;

    {
        const uint4* gh = Eh + (size_t)cb * (VCH * 4);
#pragma unroll
        for (int i = 0; i < 4; ++i) {
            int c = tid + i * TPB;
            int r = c >> 2, q = c & 3;
            sEh[(r << 2) | (q ^ ((r >> 1) & 3))] = gh[c];
        }
    }

    const int lane = tid & 63;
    const int wv = tid >> 6;
    const int zt0 = (zb * 4 + wv) * 4;

    f16x8 Bh[4];
    float thr[4];
#pragma unroll
    for (int i = 0; i < 4; ++i) {
        Bh[i] = ZFh[(size_t)(zt0 + i) * 64 + lane];
        thr[i] = unfkey(rowmax[(size_t)(zt0 + i) * 16 + (lane & 15)]) - DELTA;
    }
    __syncthreads();

    const int r15 = lane & 15, qq = lane >> 4;
    const int laneA = (r15 << 2) | (qq ^ ((r15 >> 1) & 3));

#pragma unroll
    for (int ct = 0; ct < VCH / 16; ++ct) {
        uint4 araw = sEh[ct * 64 + laneA];
        f16x8 Ah = *(const f16x8*)&araw;
#pragma unroll
        for (int i = 0; i < 4; ++i) {
            f32x4 acc = {0.f, 0.f, 0.f, 0.f};
            acc = __builtin_amdgcn_mfma_f32_16x16x32_f16(Ah, Bh[i], acc, 0, 0, 0);
            float t4 = fmaxf(fmaxf(acc[0], acc[1]), fmaxf(acc[2], acc[3]));
            if (__any(t4 >= thr[i])) {
#pragma unroll
                for (int r = 0; r < 4; ++r) {
                    if (acc[r] >= thr[i]) {
                        int code = cb * VCH + ct * 16 + qq * 4 + r;
                        int row = (zt0 + i) * 16 + r15;
                        const float4* er = (const float4*)e + (size_t)code * 8;
                        const float4* zr = (const float4*)Zn + (size_t)row * 8;
                        float s = 0.f;
#pragma unroll
                        for (int q = 0; q < 8; ++q) {
                            float4 a = er[q], b = zr[q];
                            s = fmaf(a.x, b.x, s); s = fmaf(a.y, b.y, s);
                            s = fmaf(a.z, b.z, s); s = fmaf(a.w, b.w, s);
                        }
                        unsigned long long key =
                            ((unsigned long long)fkey(s) << 32) |
                            (unsigned int)(Vm1 - code);
                        atomicMax(&packed[row], key);
                    }
                }
            }
        }
    }
}

// Final: decode idx, gather normalized code, write z_q (b,c,h,w), partial loss per block.
__global__ void kfinal(const float* __restrict__ z, const float* __restrict__ e,
                       const unsigned long long* __restrict__ packed,
                       float* __restrict__ out, float* __restrict__ partial, int V) {
    __shared__ float red[TPB];
    int n = blockIdx.x * TPB + threadIdx.x;
    int b = n >> 10, hw = n & 1023;
    unsigned long long p = packed[n];
    int idx = (V - 1) - (int)(unsigned int)(p & 0xFFFFFFFFull);

    float zrow[ZC];
    float s = 0.f;
#pragma unroll
    for (int c = 0; c < ZC; ++c) {
        float t = z[((size_t)b * ZC + c) * HW + hw];
        zrow[c] = t;
        s += t * t;
    }
    float inv = 1.0f / fmaxf(sqrtf(s), 1e-12f);

    const float4* er = reinterpret_cast<const float4*>(e) + (size_t)idx * 8;
    float loss = 0.f;
#pragma unroll
    for (int q = 0; q < 8; ++q) {
        float4 ev = er[q];
        float d0 = ev.x - zrow[4 * q + 0] * inv;
        float d1 = ev.y - zrow[4 * q + 1] * inv;
        float d2 = ev.z - zrow[4 * q + 2] * inv;
        float d3 = ev.w - zrow[4 * q + 3] * inv;
        loss += d0 * d0 + d1 * d1 + d2 * d2 + d3 * d3;
        out[((size_t)b * ZC + (4 * q + 0)) * HW + hw] = ev.x;
        out[((size_t)b * ZC + (4 * q + 1)) * HW + hw] = ev.y;
        out[((size_t)b * ZC + (4 * q + 2)) * HW + hw] = ev.z;
        out[((size_t)b * ZC + (4 * q + 3)) * HW + hw] = ev.w;
    }

    red[threadIdx.x] = loss;
    __syncthreads();
    for (int st = TPB / 2; st > 0; st >>= 1) {
        if (threadIdx.x < st) red[threadIdx.x] += red[threadIdx.x + st];
        __syncthreads();
    }
    if (threadIdx.x == 0) partial[blockIdx.x] = red[0];
}

__global__ void kloss(const float* __restrict__ partial, float* __restrict__ out,
                      int nblocks, int NC) {
    int lane = threadIdx.x;
    float s = (lane < nblocks) ? partial[lane] : 0.f;
#pragma unroll
    for (int off = 32; off > 0; off >>= 1) s += __shfl_down(s, off);
    if (lane == 0) {
        float mean = s / (float)NC;
        out[NC] = mean;             // vq_loss
        out[NC + 1] = 0.25f * mean; // commit_loss (BETA = 0.25)
    }
}

extern "C" void kernel_launch(void* const* d_in, const int* in_sizes, int n_in,
                              void* d_out, int out_size, void* d_ws, size_t ws_size,
                              hipStream_t stream) {
    const float* z = (const float*)d_in[0];
    const float* emb = (const float*)d_in[1];
    float* out = (float*)d_out;

    const int N = in_sizes[0] / ZC;   // 16384
    const int V = in_sizes[1] / ZC;   // 8192

    // workspace layout (16B-aligned)
    char* ws = (char*)d_ws;
    float* e = (float*)ws;                                    // 1 MB
    f16* Eh = (f16*)(ws + (size_t)V * ZC * 4);                // 0.5 MB
    f16x8* ZFh = (f16x8*)(ws + (size_t)V * ZC * 6);           // 1 MB (N*4 frags)
    float* Zn = (float*)(ws + (size_t)V * ZC * 6 + (size_t)N * ZC * 2);   // 2 MB
    unsigned int* rowmax =
        (unsigned int*)(ws + (size_t)V * ZC * 6 + (size_t)N * ZC * 6);    // 64 KB
    unsigned long long* packed =
        (unsigned long long*)((char*)rowmax + (size_t)N * 4);             // 128 KB
    float* partial = (float*)((char*)packed + (size_t)N * 8);

    const int zblocks = (N * 4 + TPB - 1) / TPB;   // 256
    const int eblocks = (V + TPB - 1) / TPB;       // 32
    const int grid = (V / VCH) * (N / ZROWS_BLK);  // 32 * 64 = 2048

    kprep<<<zblocks + eblocks, TPB, 0, stream>>>(z, emb, e, Eh, ZFh, Zn,
                                                 packed, rowmax, N, V, zblocks);
    kscreen<<<grid, TPB, 0, stream>>>(ZFh, (const uint4*)Eh, rowmax);
    krefine<<<grid, TPB, 0, stream>>>(ZFh, (const uint4*)Eh, e, Zn, rowmax,
                                      packed, V - 1);
    kfinal<<<N / TPB, TPB, 0, stream>>>(z, e, packed, out, partial, V);
    kloss<<<1, 64, 0, stream>>>(partial, out, N / TPB, N * ZC);
}